// Round 1
// baseline (196.191 us; speedup 1.0000x reference)
//
#include <hip/hip_runtime.h>

#define BATCH 2
#define SEQ   384
#define HID   128
#define TABLE (2 * SEQ + 1)   // 769
#define KPB   8               // k-values per block in gather kernel

// Phase 1: T[tab][t][h] = dot(pe_tab[t,:], W[h, tab*HID : (tab+1)*HID]) (+ b[h] on tab 0)
// grid (TABLE, 4), block HID
__global__ void precompute_tables(const float* __restrict__ pe_ss,
                                  const float* __restrict__ pe_se,
                                  const float* __restrict__ pe_es,
                                  const float* __restrict__ pe_ee,
                                  const float* __restrict__ W,
                                  const float* __restrict__ b,
                                  float* __restrict__ T) {
    const int t   = blockIdx.x;   // table row 0..768
    const int tab = blockIdx.y;   // 0..3
    const int h   = threadIdx.x;  // 0..127

    const float* pe = (tab == 0) ? pe_ss : (tab == 1) ? pe_se
                    : (tab == 2) ? pe_es : pe_ee;

    __shared__ float s_pe[HID];
    s_pe[h] = pe[(size_t)t * HID + h];
    __syncthreads();

    // W is [HID, 4*HID] row-major; thread h streams W[h, tab*HID + f]
    const float4* w4 = (const float4*)(W + (size_t)h * (4 * HID) + tab * HID);
    const float4* p4 = (const float4*)s_pe;

    float acc = (tab == 0) ? b[h] : 0.0f;
#pragma unroll
    for (int f = 0; f < HID / 4; ++f) {
        float4 w = w4[f];
        float4 p = p4[f];
        acc += w.x * p.x + w.y * p.y + w.z * p.z + w.w * p.w;
    }
    T[((size_t)tab * TABLE + t) * HID + h] = acc;
}

// Phase 2: out[b,q,k,h] = relu(T0[i_ss,h] + T1[i_se,h] + T2[i_es,h] + T3[i_ee,h])
// grid (SEQ/KPB, SEQ, BATCH), block 256 (= KPB k-values x 32 float4 lanes)
__global__ void gather_fuse(const int* __restrict__ pos_s,
                            const int* __restrict__ pos_e,
                            const float* __restrict__ T,
                            float* __restrict__ out) {
    const int kk = threadIdx.x >> 5;   // 0..KPB-1
    const int h4 = threadIdx.x & 31;   // float4 lane within hidden dim
    const int k  = blockIdx.x * KPB + kk;
    const int q  = blockIdx.y;
    const int bb = blockIdx.z;

    const int ps_q = pos_s[bb * SEQ + q];
    const int pe_q = pos_e[bb * SEQ + q];
    const int ps_k = pos_s[bb * SEQ + k];
    const int pe_k = pos_e[bb * SEQ + k];

    const int R = HID / 4;   // 32 float4 per table row
    const float4* T4 = (const float4*)T;
    const size_t TR = (size_t)TABLE * R;

    float4 a = T4[         (size_t)(ps_q - ps_k + SEQ) * R + h4];
    float4 c = T4[    TR + (size_t)(ps_q - pe_k + SEQ) * R + h4];
    float4 d = T4[2 * TR + (size_t)(pe_q - ps_k + SEQ) * R + h4];
    float4 e = T4[3 * TR + (size_t)(pe_q - pe_k + SEQ) * R + h4];

    float4 r;
    r.x = fmaxf(a.x + c.x + d.x + e.x, 0.0f);
    r.y = fmaxf(a.y + c.y + d.y + e.y, 0.0f);
    r.z = fmaxf(a.z + c.z + d.z + e.z, 0.0f);
    r.w = fmaxf(a.w + c.w + d.w + e.w, 0.0f);

    ((float4*)out)[(((size_t)bb * SEQ + q) * SEQ + k) * R + h4] = r;
}

extern "C" void kernel_launch(void* const* d_in, const int* in_sizes, int n_in,
                              void* d_out, int out_size, void* d_ws, size_t ws_size,
                              hipStream_t stream) {
    const int*   pos_s = (const int*)d_in[0];
    const int*   pos_e = (const int*)d_in[1];
    const float* pe_ss = (const float*)d_in[2];
    const float* pe_se = (const float*)d_in[3];
    const float* pe_es = (const float*)d_in[4];
    const float* pe_ee = (const float*)d_in[5];
    const float* W     = (const float*)d_in[6];
    const float* b     = (const float*)d_in[7];
    float*       out   = (float*)d_out;
    float*       T     = (float*)d_ws;   // 4 * TABLE * HID floats ≈ 1.5 MB

    precompute_tables<<<dim3(TABLE, 4), HID, 0, stream>>>(
        pe_ss, pe_se, pe_es, pe_ee, W, b, T);

    gather_fuse<<<dim3(SEQ / KPB, SEQ, BATCH), 256, 0, stream>>>(
        pos_s, pos_e, T, out);
}

// Round 3
// 196.062 us; speedup vs baseline: 1.0007x; 1.0007x over previous
//
#include <hip/hip_runtime.h>

#define BATCH 2
#define SEQ   384
#define HID   128
#define TABLE (2 * SEQ + 1)   // 769
#define KPB   8               // k-values per block in gather kernel
#define TPB   8               // t-rows per block in precompute

typedef float vfloat4 __attribute__((ext_vector_type(4)));  // native vec for builtins

// ws layout: T  = 4 * TABLE * HID floats (1.575 MB)
//            Wt = 4 * HID * HID floats   (256 KB), transposed W

// Kernel 0: Wt[tab][f][h] = W[h][tab*HID + f]   (W row-major [HID, 4*HID])
__global__ void transpose_w(const float* __restrict__ W, float* __restrict__ Wt) {
    const int idx = blockIdx.x * 256 + threadIdx.x;  // tab*16384 + f*128 + h
    const int h   = idx & (HID - 1);
    const int f   = (idx >> 7) & (HID - 1);
    const int tab = idx >> 14;
    Wt[idx] = W[h * (4 * HID) + tab * HID + f];
}

// Kernel 1: T[tab][t][h] = sum_f pe_tab[t][f] * Wt[tab][f][h]  (+ b[h] for tab 0)
// grid (ceil(TABLE/TPB), 4), block HID. Wt reads lane-coalesced; pe reads wave-uniform.
__global__ void precompute_tables(const float* __restrict__ pe_ss,
                                  const float* __restrict__ pe_se,
                                  const float* __restrict__ pe_es,
                                  const float* __restrict__ pe_ee,
                                  const float* __restrict__ Wt,
                                  const float* __restrict__ b,
                                  float* __restrict__ T) {
    const int t0  = blockIdx.x * TPB;
    const int tab = blockIdx.y;
    const int h   = threadIdx.x;

    const float* pe = (tab == 0) ? pe_ss : (tab == 1) ? pe_se
                    : (tab == 2) ? pe_es : pe_ee;

    const float* pr[TPB];
#pragma unroll
    for (int r = 0; r < TPB; ++r) {
        int tr = t0 + r; if (tr > TABLE - 1) tr = TABLE - 1;
        pr[r] = pe + (size_t)tr * HID;
    }

    float acc[TPB];
    const float binit = (tab == 0) ? b[h] : 0.0f;
#pragma unroll
    for (int r = 0; r < TPB; ++r) acc[r] = binit;

    const float* wcol = Wt + ((size_t)tab * HID) * HID + h;  // stride HID over f
#pragma unroll 4
    for (int f = 0; f < HID; ++f) {
        const float wf = wcol[(size_t)f * HID];
#pragma unroll
        for (int r = 0; r < TPB; ++r) acc[r] += pr[r][f] * wf;
    }

#pragma unroll
    for (int r = 0; r < TPB; ++r) {
        const int t = t0 + r;
        if (t < TABLE) T[((size_t)tab * TABLE + t) * HID + h] = acc[r];
    }
}

// Kernel 2: out[b,q,k,h] = relu(T0[i_ss,h] + T1[i_se,h] + T2[i_es,h] + T3[i_ee,h])
// grid (SEQ/KPB, SEQ, BATCH), block 256 (= KPB k x 32 float4 lanes).
// Nontemporal stores keep the 151 MB write stream out of L2 so T stays resident.
__global__ void gather_fuse(const int* __restrict__ pos_s,
                            const int* __restrict__ pos_e,
                            const float* __restrict__ T,
                            float* __restrict__ out) {
    const int kk = threadIdx.x >> 5;
    const int h4 = threadIdx.x & 31;
    const int k  = blockIdx.x * KPB + kk;
    const int q  = blockIdx.y;
    const int bb = blockIdx.z;

    const int ps_q = pos_s[bb * SEQ + q];
    const int pe_q = pos_e[bb * SEQ + q];
    const int ps_k = pos_s[bb * SEQ + k];
    const int pe_k = pos_e[bb * SEQ + k];

    const int R = HID / 4;
    const vfloat4* T4 = (const vfloat4*)T;
    const size_t TR = (size_t)TABLE * R;

    vfloat4 a = T4[         (size_t)(ps_q - ps_k + SEQ) * R + h4];
    vfloat4 c = T4[    TR + (size_t)(ps_q - pe_k + SEQ) * R + h4];
    vfloat4 d = T4[2 * TR + (size_t)(pe_q - ps_k + SEQ) * R + h4];
    vfloat4 e = T4[3 * TR + (size_t)(pe_q - pe_k + SEQ) * R + h4];

    vfloat4 s = a + c + d + e;
    vfloat4 r;
    r.x = fmaxf(s.x, 0.0f);
    r.y = fmaxf(s.y, 0.0f);
    r.z = fmaxf(s.z, 0.0f);
    r.w = fmaxf(s.w, 0.0f);

    vfloat4* op = (vfloat4*)out + (((size_t)bb * SEQ + q) * SEQ + k) * R + h4;
    __builtin_nontemporal_store(r, op);
}

extern "C" void kernel_launch(void* const* d_in, const int* in_sizes, int n_in,
                              void* d_out, int out_size, void* d_ws, size_t ws_size,
                              hipStream_t stream) {
    const int*   pos_s = (const int*)d_in[0];
    const int*   pos_e = (const int*)d_in[1];
    const float* pe_ss = (const float*)d_in[2];
    const float* pe_se = (const float*)d_in[3];
    const float* pe_es = (const float*)d_in[4];
    const float* pe_ee = (const float*)d_in[5];
    const float* W     = (const float*)d_in[6];
    const float* b     = (const float*)d_in[7];
    float*       out   = (float*)d_out;

    float* T  = (float*)d_ws;                       // 4*769*128 floats
    float* Wt = T + (size_t)4 * TABLE * HID;        // 4*128*128 floats

    transpose_w<<<dim3((4 * HID * HID) / 256), 256, 0, stream>>>(W, Wt);

    precompute_tables<<<dim3((TABLE + TPB - 1) / TPB, 4), HID, 0, stream>>>(
        pe_ss, pe_se, pe_es, pe_ee, Wt, b, T);

    gather_fuse<<<dim3(SEQ / KPB, SEQ, BATCH), 256, 0, stream>>>(
        pos_s, pos_e, T, out);
}

// Round 4
// 194.585 us; speedup vs baseline: 1.0083x; 1.0076x over previous
//
#include <hip/hip_runtime.h>

#define BATCH 2
#define SEQ   384
#define HID   128
#define TABLE (2 * SEQ + 1)   // 769
#define KPB   8               // k-values per block in gather kernel
#define TPB   8               // t-rows per block in precompute

typedef unsigned int  uint32;
typedef unsigned short ushort16;
typedef float  vfloat4 __attribute__((ext_vector_type(4)));
typedef uint32 vuint2  __attribute__((ext_vector_type(2)));

// ws layout: T  (bf16) = 4 * TABLE * HID ushort  (787 KB)
//            Wt (f32)  = 4 * HID * HID float     (256 KB)

// bf16 helpers: bf16 is the high half of fp32 — unpack is exact.
__device__ __forceinline__ float blo(uint32 u) { return __uint_as_float(u << 16); }
__device__ __forceinline__ float bhi(uint32 u) { return __uint_as_float(u & 0xFFFF0000u); }
__device__ __forceinline__ ushort16 f2bf_rn(float f) {
    uint32 u = __float_as_uint(f);
    u += 0x7FFFu + ((u >> 16) & 1u);   // round-to-nearest-even
    return (ushort16)(u >> 16);
}

// Kernel 0: Wt[tab][f][h] = W[h][tab*HID + f]   (W row-major [HID, 4*HID])
__global__ void transpose_w(const float* __restrict__ W, float* __restrict__ Wt) {
    const int idx = blockIdx.x * 256 + threadIdx.x;  // tab*16384 + f*128 + h
    const int h   = idx & (HID - 1);
    const int f   = (idx >> 7) & (HID - 1);
    const int tab = idx >> 14;
    Wt[idx] = W[h * (4 * HID) + tab * HID + f];
}

// Kernel 1: T[tab][t][h] = bf16( sum_f pe_tab[t][f] * Wt[tab][f][h] (+ b[h] tab0) )
__global__ void precompute_tables(const float* __restrict__ pe_ss,
                                  const float* __restrict__ pe_se,
                                  const float* __restrict__ pe_es,
                                  const float* __restrict__ pe_ee,
                                  const float* __restrict__ Wt,
                                  const float* __restrict__ b,
                                  ushort16* __restrict__ T) {
    const int t0  = blockIdx.x * TPB;
    const int tab = blockIdx.y;
    const int h   = threadIdx.x;

    const float* pe = (tab == 0) ? pe_ss : (tab == 1) ? pe_se
                    : (tab == 2) ? pe_es : pe_ee;

    const float* pr[TPB];
#pragma unroll
    for (int r = 0; r < TPB; ++r) {
        int tr = t0 + r; if (tr > TABLE - 1) tr = TABLE - 1;
        pr[r] = pe + (size_t)tr * HID;
    }

    float acc[TPB];
    const float binit = (tab == 0) ? b[h] : 0.0f;
#pragma unroll
    for (int r = 0; r < TPB; ++r) acc[r] = binit;

    const float* wcol = Wt + ((size_t)tab * HID) * HID + h;  // lane-coalesced
#pragma unroll 4
    for (int f = 0; f < HID; ++f) {
        const float wf = wcol[(size_t)f * HID];
#pragma unroll
        for (int r = 0; r < TPB; ++r) acc[r] += pr[r][f] * wf;
    }

#pragma unroll
    for (int r = 0; r < TPB; ++r) {
        const int t = t0 + r;
        if (t < TABLE) T[((size_t)tab * TABLE + t) * HID + h] = f2bf_rn(acc[r]);
    }
}

// Kernel 2: out[b,q,k,h] = relu(T0[i_ss,h] + T1[i_se,h] + T2[i_es,h] + T3[i_ee,h])
// T is bf16: 787 KB total -> L2-resident; reads are 302 MB instead of 604 MB.
// grid (SEQ/KPB, SEQ, BATCH), block 256. Lane h4 covers h in [4*h4, 4*h4+4):
// one 8-byte (vuint2 = 4 bf16) load per table, 32 lanes x 8 B = full 256 B row.
__global__ void gather_fuse(const int* __restrict__ pos_s,
                            const int* __restrict__ pos_e,
                            const ushort16* __restrict__ T,
                            float* __restrict__ out) {
    const int kk = threadIdx.x >> 5;
    const int h4 = threadIdx.x & 31;
    const int k  = blockIdx.x * KPB + kk;
    const int q  = blockIdx.y;
    const int bb = blockIdx.z;

    const int ps_q = pos_s[bb * SEQ + q];
    const int pe_q = pos_e[bb * SEQ + q];
    const int ps_k = pos_s[bb * SEQ + k];
    const int pe_k = pos_e[bb * SEQ + k];

    // one table row = 128 bf16 = 32 vuint2
    const vuint2* T2 = (const vuint2*)T;
    const size_t TR = (size_t)TABLE * 32;

    vuint2 a = T2[         (size_t)(ps_q - ps_k + SEQ) * 32 + h4];
    vuint2 c = T2[    TR + (size_t)(ps_q - pe_k + SEQ) * 32 + h4];
    vuint2 d = T2[2 * TR + (size_t)(pe_q - ps_k + SEQ) * 32 + h4];
    vuint2 e = T2[3 * TR + (size_t)(pe_q - pe_k + SEQ) * 32 + h4];

    vfloat4 r;
    r.x = fmaxf(blo(a.x) + blo(c.x) + blo(d.x) + blo(e.x), 0.0f);
    r.y = fmaxf(bhi(a.x) + bhi(c.x) + bhi(d.x) + bhi(e.x), 0.0f);
    r.z = fmaxf(blo(a.y) + blo(c.y) + blo(d.y) + blo(e.y), 0.0f);
    r.w = fmaxf(bhi(a.y) + bhi(c.y) + bhi(d.y) + bhi(e.y), 0.0f);

    vfloat4* op = (vfloat4*)out + (((size_t)bb * SEQ + q) * SEQ + k) * 32 + h4;
    __builtin_nontemporal_store(r, op);
}

extern "C" void kernel_launch(void* const* d_in, const int* in_sizes, int n_in,
                              void* d_out, int out_size, void* d_ws, size_t ws_size,
                              hipStream_t stream) {
    const int*   pos_s = (const int*)d_in[0];
    const int*   pos_e = (const int*)d_in[1];
    const float* pe_ss = (const float*)d_in[2];
    const float* pe_se = (const float*)d_in[3];
    const float* pe_es = (const float*)d_in[4];
    const float* pe_ee = (const float*)d_in[5];
    const float* W     = (const float*)d_in[6];
    const float* b     = (const float*)d_in[7];
    float*       out   = (float*)d_out;

    ushort16* T  = (ushort16*)d_ws;                       // 4*769*128 bf16 = 787456 B
    float*    Wt = (float*)((char*)d_ws + (size_t)4 * TABLE * HID * sizeof(ushort16));

    transpose_w<<<dim3((4 * HID * HID) / 256), 256, 0, stream>>>(W, Wt);

    precompute_tables<<<dim3((TABLE + TPB - 1) / TPB, 4), HID, 0, stream>>>(
        pe_ss, pe_se, pe_es, pe_ee, Wt, b, T);

    gather_fuse<<<dim3(SEQ / KPB, SEQ, BATCH), 256, 0, stream>>>(
        pos_s, pos_e, T, out);
}